// Round 5
// baseline (160.798 us; speedup 1.0000x reference)
//
#include <hip/hip_runtime.h>

// RandRotate90_3D: per-sample rot90^k (k = koefs[b] in [0,3]) on axes (D,H)
// of [B=16, D=128, H=128, W=128] float32, applied to 3 tensors.
// Closed form: k=0: out[i][j]=in[i][j]; k=1: out[i][j]=in[j][127-i];
//              k=2: out[i][j]=in[127-i][127-j]; k=3: out[i][j]=in[127-j][i]
// W axis untouched -> row granularity 512B. Pure gather.
//
// R5: per-sample adaptive lane mapping. k is wave-uniform per sample, so pick
// the thread->(i,j) view per b:
//   k in {0,2}: J-fast (i=slow,j=fast)  -> reads AND writes contiguous.
//   k in {1,3}: I-fast (j=slow,i=fast)  -> src rows consecutive in the fast
//               index -> READS fully sequential; writes take the 512B/64KB
//               scatter (posted NT stores tolerate it better than demand
//               loads).
// Non-temporal both sides (805MB streaming, zero reuse). unroll 4 (R3's best;
// unroll 8 regressed in R4).

typedef float f32x4 __attribute__((ext_vector_type(4)));

#define NN 128
#define W4 32                        // 128 floats / 4 per float4
#define SAMPLE (NN * NN * W4)        // 2^19 float4 per sample
#define PER_TENSOR (16 * SAMPLE)     // 2^23 float4 per tensor
#define TPB 256
#define BLOCKS 2048                  // 2048*256 threads == SAMPLE exactly

__global__ __launch_bounds__(TPB) void rot90_gather_kernel(
    const f32x4* __restrict__ vol,
    const f32x4* __restrict__ msk,
    const f32x4* __restrict__ skl,
    const int* __restrict__ koefs,
    f32x4* __restrict__ out)
{
    const int tid = blockIdx.x * TPB + threadIdx.x;   // [0, 2^19)
    const int w4 = tid & 31;
    const int rA = (tid >> 5) & 127;   // fast row index (advances across lanes/waves)
    const int rB = (tid >> 12) & 127;  // slow row index

    // J-fast view: i = rB, j = rA  (dst contiguous in fast index)
    const int dJ = (rB * NN + rA) * W4 + w4;
    const int s0 = dJ;                                        // k=0 src
    const int s2 = ((127 - rB) * NN + (127 - rA)) * W4 + w4;  // k=2 src (contig, desc)

    // I-fast view: i = rA, j = rB  (src contiguous in fast index, dst strided)
    const int dI = (rA * NN + rB) * W4 + w4;
    const int s1 = (rB * NN + (127 - rA)) * W4 + w4;          // k=1 src: row j*128+(127-i)
    const int s3 = ((127 - rB) * NN + rA) * W4 + w4;          // k=3 src: row (127-j)*128+i

#pragma unroll
    for (int t = 0; t < 3; ++t) {
        const f32x4* __restrict__ in = (t == 0) ? vol : (t == 1) ? msk : skl;
        f32x4* __restrict__ ot = out + t * PER_TENSOR;
#pragma unroll 4
        for (int b = 0; b < 16; ++b) {
            const int k = koefs[b];   // wave-uniform scalar load
            const int so = (k == 1 ? s1 : k == 2 ? s2 : k == 3 ? s3 : s0) + b * SAMPLE;
            const int dd = ((k == 1 || k == 3) ? dI : dJ) + b * SAMPLE;
            const f32x4 v = __builtin_nontemporal_load(in + so);
            __builtin_nontemporal_store(v, ot + dd);
        }
    }
}

extern "C" void kernel_launch(void* const* d_in, const int* in_sizes, int n_in,
                              void* d_out, int out_size, void* d_ws, size_t ws_size,
                              hipStream_t stream) {
    const f32x4* vol = (const f32x4*)d_in[0];
    const f32x4* msk = (const f32x4*)d_in[1];
    const f32x4* skl = (const f32x4*)d_in[2];
    const int* koefs  = (const int*)d_in[3];
    f32x4* out = (f32x4*)d_out;

    rot90_gather_kernel<<<BLOCKS, TPB, 0, stream>>>(vol, msk, skl, koefs, out);
}

// Round 6
// 133.222 us; speedup vs baseline: 1.2070x; 1.2070x over previous
//
#include <hip/hip_runtime.h>

// RandRotate90_3D: per-sample rot90^k (k = koefs[b] in [0,3]) on axes (D,H)
// of [B=16, D=128, H=128, W=128] float32, applied to 3 tensors.
// Closed form: k=0: out[i][j]=in[i][j]; k=1: out[i][j]=in[j][127-i];
//              k=2: out[i][j]=in[127-i][127-j]; k=3: out[i][j]=in[127-j][i]
// W axis untouched -> row granularity 512B.
//
// R6: blocked transpose through LDS for odd k. One WG per 8x8 (i,j)-row tile
// x full W (32KB). For k in {1,3} the tile's source footprint is a dense 8x8
// row block -> read 8x contiguous-4KB chunks into LDS, barrier, write 8x
// contiguous-4KB chunks with permuted LDS reads (2-way bank alias = free).
// k in {0,2} bypass LDS (already contiguous both sides). k is uniform per
// block -> scalar branch. NT on all global accesses (805MB, zero reuse).
// History: R3 direct gather 145.7us (reads 512B/64KB-strided for odd k);
// R5 swapped scatter to writes -> 160.8us (NT stores hate 512B stride).

typedef float f32x4 __attribute__((ext_vector_type(4)));

#define NN 128
#define W4 32                        // 128 floats / 4 per float4
#define SAMPLE (NN * NN * W4)        // 2^19 float4 per sample
#define PER_TENSOR (16 * SAMPLE)     // 2^23 float4 per tensor
#define TPB 256
#define NWG (3 * 16 * 256)           // tensors x samples x (16x16 tiles)

__global__ __launch_bounds__(TPB) void rot90_tile_kernel(
    const f32x4* __restrict__ vol,
    const f32x4* __restrict__ msk,
    const f32x4* __restrict__ skl,
    const int* __restrict__ koefs,
    f32x4* __restrict__ out)
{
    __shared__ f32x4 lds[2048];      // 8 rows-of-8 x 256 float4 = 32KB

    const int wg   = blockIdx.x;
    const int tile = wg & 255;
    const int b    = (wg >> 8) & 15;
    const int t    = wg >> 12;
    const int i0   = ((tile >> 4) & 15) * 8;
    const int j0   = (tile & 15) * 8;
    const int tid  = threadIdx.x;
    const int jj   = (tid >> 5) & 7;  // row-within-chunk
    const int w4   = tid & 31;

    const int k = koefs[b];           // uniform per block
    const f32x4* __restrict__ in = ((t == 0) ? vol : (t == 1) ? msk : skl) + b * SAMPLE;
    f32x4* __restrict__ ot = out + t * PER_TENSOR + b * SAMPLE;

    if (k == 0) {
#pragma unroll
        for (int it = 0; it < 8; ++it) {
            const int a = ((i0 + it) * NN + j0 + jj) * W4 + w4;
            __builtin_nontemporal_store(__builtin_nontemporal_load(in + a), ot + a);
        }
    } else if (k == 2) {
#pragma unroll
        for (int it = 0; it < 8; ++it) {
            const int d = ((i0 + it) * NN + j0 + jj) * W4 + w4;
            const int s = ((127 - (i0 + it)) * NN + (127 - (j0 + jj))) * W4 + w4;
            __builtin_nontemporal_store(__builtin_nontemporal_load(in + s), ot + d);
        }
    } else if (k == 1) {
        // src footprint: si in [j0, j0+8), sj in [sjlo, sjlo+8), sjlo = 120-i0
        const int sjlo = 120 - i0;
#pragma unroll
        for (int it = 0; it < 8; ++it) {   // read: 4KB contiguous per iter
            const int s = ((j0 + it) * NN + sjlo + jj) * W4 + w4;
            lds[it * 256 + tid] = __builtin_nontemporal_load(in + s);
        }
        __syncthreads();
#pragma unroll
        for (int it = 0; it < 8; ++it) {   // write: 4KB contiguous per iter
            const int d = ((i0 + it) * NN + j0 + jj) * W4 + w4;
            // value = in[j][127-i] = lds[(j-j0)*256 + (7-it)*32 + w4]
            __builtin_nontemporal_store(lds[jj * 256 + (7 - it) * 32 + w4], ot + d);
        }
    } else { // k == 3
        // src footprint: si in [silo, silo+8), sj in [i0, i0+8), silo = 120-j0
        const int silo = 120 - j0;
#pragma unroll
        for (int it = 0; it < 8; ++it) {   // read: 4KB contiguous per iter
            const int s = ((silo + it) * NN + i0 + jj) * W4 + w4;
            lds[it * 256 + tid] = __builtin_nontemporal_load(in + s);
        }
        __syncthreads();
#pragma unroll
        for (int it = 0; it < 8; ++it) {   // write: 4KB contiguous per iter
            const int d = ((i0 + it) * NN + j0 + jj) * W4 + w4;
            // value = in[127-j][i] = lds[(7-jj)*256 + it*32 + w4]
            __builtin_nontemporal_store(lds[(7 - jj) * 256 + it * 32 + w4], ot + d);
        }
    }
}

extern "C" void kernel_launch(void* const* d_in, const int* in_sizes, int n_in,
                              void* d_out, int out_size, void* d_ws, size_t ws_size,
                              hipStream_t stream) {
    const f32x4* vol = (const f32x4*)d_in[0];
    const f32x4* msk = (const f32x4*)d_in[1];
    const f32x4* skl = (const f32x4*)d_in[2];
    const int* koefs  = (const int*)d_in[3];
    f32x4* out = (f32x4*)d_out;

    rot90_tile_kernel<<<NWG, TPB, 0, stream>>>(vol, msk, skl, koefs, out);
}